// Round 9
// baseline (655.975 us; speedup 1.0000x reference)
//
#include <hip/hip_runtime.h>
#include <hip/hip_bf16.h>

#define A_TOTAL  200000
#define BSEG     100
#define FR_      256
#define DIN_     512
#define H_       256
#define P_       6
#define TA       32
#define NTHREADS 512

#define SNI_STRIDE 1040   // 512 bf16 = 1024B + 16B pad
#define SH_STRIDE  528    // 256 bf16 = 512B + 16B pad

typedef float f32x4  __attribute__((ext_vector_type(4)));
typedef short bf16x8 __attribute__((ext_vector_type(8)));

__device__ __forceinline__ unsigned short f2bf(float x) {
    union { float f; unsigned int u; } c; c.f = x;
    unsigned int u = c.u;
    return (unsigned short)((u + 0x7fffu + ((u >> 16) & 1u)) >> 16);
}
__device__ __forceinline__ unsigned int pk2(float a, float b) {   // v_cvt_pk_bf16_f32
    union { __hip_bfloat162 h2; unsigned int u; } c;
    c.h2 = __float22bfloat162_rn(float2{a, b});
    return c.u;
}
// 5-op tanh: mul, v_exp, add, v_rcp, fma. rcp is 1-ulp -> fine for bf16 output.
__device__ __forceinline__ float fast_tanh(float x) {
    float e = __builtin_amdgcn_exp2f(x * 2.88539008177793f);  // e^{2x}
    float r = __builtin_amdgcn_rcpf(e + 1.f);
    return __builtin_fmaf(-2.f, r, 1.f);
}
__device__ __forceinline__ f32x4 mfma16(bf16x8 a, bf16x8 b, f32x4 c) {
    return __builtin_amdgcn_mfma_f32_16x16x32_bf16(a, b, c, 0, 0, 0);
}

// ---------------------------------------------------------------------------
// Prep: W1/W2 -> bf16 fragment-linear layout; prefix-sum num_angles; zero out.
// B-frag for 16x16x32: lane l holds B[k = s*32 + 8*(l>>4) + j][n = nt*16 + (l&15)]
// stored as wt[p][s][nt][l][j] (16B per lane -> coalesced 1KB wave loads).
// ---------------------------------------------------------------------------
__global__ void prep_kernel(const float* __restrict__ W1, const float* __restrict__ W2,
                            const int* __restrict__ num_angles, float* __restrict__ out,
                            int* __restrict__ prefix,
                            unsigned short* __restrict__ wt1, unsigned short* __restrict__ wt2) {
    int tt = blockIdx.x * blockDim.x + threadIdx.x;
    if (blockIdx.x == 0) {
        if (threadIdx.x < BSEG) out[threadIdx.x] = 0.f;
        if (threadIdx.x == 0) {
            int acc = 0; prefix[0] = 0;
            for (int i = 0; i < BSEG; ++i) { acc += num_angles[i]; prefix[i + 1] = acc; }
        }
    }
    if (tt < 98304) {                       // W1: 6 p * 16 s * 16 nt * 64 lanes
        int l  = tt & 63;
        int nt = (tt >> 6) & 15;
        int s  = (tt >> 10) & 15;
        int p  = tt >> 14;
        int k  = s * 32 + 8 * (l >> 4);
        int n  = nt * 16 + (l & 15);
        const float* src = W1 + ((size_t)p * DIN_ + k) * H_ + n;
        unsigned short tmp[8];
#pragma unroll
        for (int j = 0; j < 8; ++j) tmp[j] = f2bf(src[(size_t)j * H_]);
        *reinterpret_cast<uint4*>(wt1 + (size_t)tt * 8) = *reinterpret_cast<uint4*>(tmp);
    } else if (tt < 98304 + 49152) {        // W2: 6 p * 8 s * 16 nt * 64 lanes
        int t2 = tt - 98304;
        int l  = t2 & 63;
        int nt = (t2 >> 6) & 15;
        int s  = (t2 >> 10) & 7;
        int p  = t2 >> 13;
        int k  = s * 32 + 8 * (l >> 4);
        int n  = nt * 16 + (l & 15);
        const float* src = W2 + ((size_t)p * H_ + k) * H_ + n;
        unsigned short tmp[8];
#pragma unroll
        for (int j = 0; j < 8; ++j) tmp[j] = f2bf(src[(size_t)j * H_]);
        *reinterpret_cast<uint4*>(wt2 + (size_t)t2 * 8) = *reinterpret_cast<uint4*>(tmp);
    }
}

// B-prefetch: load chunk c (2 s-steps x 2 ntiles) into buffer pb.
#define LDB(pb, bp0, bp1, c)                                                     \
    {                                                                            \
        pb[0][0] = *(const bf16x8*)((bp0) + (size_t)((c) * 2 + 0) * 8192);       \
        pb[1][0] = *(const bf16x8*)((bp1) + (size_t)((c) * 2 + 0) * 8192);       \
        pb[0][1] = *(const bf16x8*)((bp0) + (size_t)((c) * 2 + 1) * 8192);       \
        pb[1][1] = *(const bf16x8*)((bp1) + (size_t)((c) * 2 + 1) * 8192);       \
    }

// ---------------------------------------------------------------------------
// Main fused kernel: TA=32 angles/block, 8 waves, wave = 32 rows x 32 cols.
// LDS ~51 KB -> 3 blocks/CU (6 waves/SIMD). Ping-pong B-prefetch; each
// stage's chunk-0 load is hoisted above the preceding barrier so L2 latency
// folds into the barrier wait.
// ---------------------------------------------------------------------------
__global__ __launch_bounds__(NTHREADS, 6)
void angle_main(const float* __restrict__ r, const float* __restrict__ xyz,
                const int* __restrict__ ang,
                const float* __restrict__ b1, const float* __restrict__ b2,
                const float* __restrict__ W3, const float* __restrict__ b3,
                float* __restrict__ out, const int* __restrict__ prefix,
                const unsigned short* __restrict__ wt1, const unsigned short* __restrict__ wt2) {
    __shared__ __align__(16) char cNI[TA * SNI_STRIDE];  // 33280 B
    __shared__ __align__(16) char cH[TA * SH_STRIDE];    // 16896 B
    __shared__ float sOut[P_ * TA];
    __shared__ float sSeg[BSEG];

    const int tid  = threadIdx.x;
    const int lane = tid & 63;
    const int w    = tid >> 6;        // wave id: owns cols [w*32, w*32+32)
    const int aB   = blockIdx.x * TA;
    const int rA   = lane & 15;       // A-frag row within 16-tile
    const int q16  = 16 * (lane >> 4);// A-frag k-subgroup byte offset

    if (tid < P_ * TA) sOut[tid] = 0.f;
    if (tid < BSEG)    sSeg[tid] = 0.f;

    // Weight B-frag base pointers for this wave (ntile pair w*2, w*2+1).
    const size_t bofs = (size_t)(w * 2 * 64 + lane) * 8;
    bf16x8 u0[2][2], u1[2][2];        // ping-pong buffers, live across barriers

    // Prefetch L1 p=0 chunk 0 before the gather barrier.
    {
        const unsigned short* bp0 = wt1 + bofs;
        LDB(u0, bp0, bp0 + 512, 0);
    }

    // ---- gather node_input = [r[a0]+r[a2], r[a1]] -> LDS bf16 ----
#pragma unroll
    for (int it = 0; it < 4; ++it) {
        int c   = it * NTHREADS + tid;       // 2048 chunks of 8 elems
        int row = c >> 6;
        int k0  = (c & 63) * 8;
        int a   = aB + row;
        int i0 = ang[3 * a], i1 = ang[3 * a + 1], i2 = ang[3 * a + 2];
        float v[8];
        if (k0 < FR_) {
            const float4* p0 = (const float4*)(r + (size_t)i0 * FR_ + k0);
            const float4* p2 = (const float4*)(r + (size_t)i2 * FR_ + k0);
            float4 x0 = p0[0], x1 = p0[1], y0 = p2[0], y1 = p2[1];
            v[0] = x0.x + y0.x; v[1] = x0.y + y0.y; v[2] = x0.z + y0.z; v[3] = x0.w + y0.w;
            v[4] = x1.x + y1.x; v[5] = x1.y + y1.y; v[6] = x1.z + y1.z; v[7] = x1.w + y1.w;
        } else {
            const float4* p1 = (const float4*)(r + (size_t)i1 * FR_ + (k0 - FR_));
            float4 x0 = p1[0], x1 = p1[1];
            v[0] = x0.x; v[1] = x0.y; v[2] = x0.z; v[3] = x0.w;
            v[4] = x1.x; v[5] = x1.y; v[6] = x1.z; v[7] = x1.w;
        }
        uint4 pk;
        pk.x = pk2(v[0], v[1]); pk.y = pk2(v[2], v[3]);
        pk.z = pk2(v[4], v[5]); pk.w = pk2(v[6], v[7]);
        *reinterpret_cast<uint4*>(cNI + row * SNI_STRIDE + k0 * 2) = pk;
    }
    __syncthreads();

    for (int p = 0; p < P_; ++p) {
        // ---------------- layer 1: [32x512] @ [512x256], wave cols w*32.. ----
        const float bias10 = b1[p * H_ + w * 32 + rA];
        const float bias11 = b1[p * H_ + w * 32 + 16 + rA];
        f32x4 acc[2][2];
        acc[0][0] = (f32x4){bias10, bias10, bias10, bias10};
        acc[1][0] = acc[0][0];
        acc[0][1] = (f32x4){bias11, bias11, bias11, bias11};
        acc[1][1] = acc[0][1];
        {
            const char* aBase = cNI + rA * SNI_STRIDE + q16;
            const unsigned short* bp0 = wt1 + (size_t)p * 131072 + bofs;
            const unsigned short* bp1 = bp0 + 512;
            // u0 holds chunk 0 (prefetched before the preceding barrier)
#pragma unroll
            for (int c = 0; c < 8; ++c) {            // 8 chunks x 2 s-steps
                if (c & 1) {
                    if (c < 7) LDB(u0, bp0, bp1, c + 1);
#pragma unroll
                    for (int js = 0; js < 2; ++js) {
                        int s = c * 2 + js;
                        bf16x8 a0 = *(const bf16x8*)(aBase + 64 * s);
                        bf16x8 a1 = *(const bf16x8*)(aBase + 16 * SNI_STRIDE + 64 * s);
                        acc[0][0] = mfma16(a0, u1[0][js], acc[0][0]);
                        acc[1][0] = mfma16(a1, u1[0][js], acc[1][0]);
                        acc[0][1] = mfma16(a0, u1[1][js], acc[0][1]);
                        acc[1][1] = mfma16(a1, u1[1][js], acc[1][1]);
                    }
                } else {
                    if (c < 7) LDB(u1, bp0, bp1, c + 1);
#pragma unroll
                    for (int js = 0; js < 2; ++js) {
                        int s = c * 2 + js;
                        bf16x8 a0 = *(const bf16x8*)(aBase + 64 * s);
                        bf16x8 a1 = *(const bf16x8*)(aBase + 16 * SNI_STRIDE + 64 * s);
                        acc[0][0] = mfma16(a0, u0[0][js], acc[0][0]);
                        acc[1][0] = mfma16(a1, u0[0][js], acc[1][0]);
                        acc[0][1] = mfma16(a0, u0[1][js], acc[0][1]);
                        acc[1][1] = mfma16(a1, u0[1][js], acc[1][1]);
                    }
                }
            }
        }
        // Prefetch L2 chunk 0 now -> latency folds into the epilogue + barrier.
        {
            const unsigned short* bp0 = wt2 + (size_t)p * 65536 + bofs;
            LDB(u0, bp0, bp0 + 512, 0);
        }
        {   // tanh + packed bf16 -> cH (D layout: row = 4*(l>>4)+i, col = l&15)
#pragma unroll
            for (int nt = 0; nt < 2; ++nt) {
                int col = w * 32 + nt * 16 + rA;
#pragma unroll
                for (int mt = 0; mt < 2; ++mt) {
                    float t0 = fast_tanh(acc[mt][nt][0]);
                    float t1 = fast_tanh(acc[mt][nt][1]);
                    float t2 = fast_tanh(acc[mt][nt][2]);
                    float t3 = fast_tanh(acc[mt][nt][3]);
                    unsigned int u01 = pk2(t0, t1);
                    unsigned int u23 = pk2(t2, t3);
                    char* base = cH + (mt * 16 + (lane >> 4) * 4) * SH_STRIDE + col * 2;
                    *(unsigned short*)(base)                 = (unsigned short)(u01 & 0xffff);
                    *(unsigned short*)(base + SH_STRIDE)     = (unsigned short)(u01 >> 16);
                    *(unsigned short*)(base + 2 * SH_STRIDE) = (unsigned short)(u23 & 0xffff);
                    *(unsigned short*)(base + 3 * SH_STRIDE) = (unsigned short)(u23 >> 16);
                }
            }
        }
        __syncthreads();

        // ---------------- layer 2: [32x256] @ [256x256] ----------------
        const float bias20 = b2[p * H_ + w * 32 + rA];
        const float bias21 = b2[p * H_ + w * 32 + 16 + rA];
        f32x4 acc2[2][2];
        acc2[0][0] = (f32x4){bias20, bias20, bias20, bias20};
        acc2[1][0] = acc2[0][0];
        acc2[0][1] = (f32x4){bias21, bias21, bias21, bias21};
        acc2[1][1] = acc2[0][1];
        {
            const char* aBase = cH + rA * SH_STRIDE + q16;
            const unsigned short* bp0 = wt2 + (size_t)p * 65536 + bofs;
            const unsigned short* bp1 = bp0 + 512;
            // u0 holds chunk 0 (prefetched before the barrier)
#pragma unroll
            for (int c = 0; c < 4; ++c) {            // 4 chunks x 2 s-steps
                if (c & 1) {
                    if (c < 3) LDB(u0, bp0, bp1, c + 1);
#pragma unroll
                    for (int js = 0; js < 2; ++js) {
                        int s = c * 2 + js;
                        bf16x8 a0 = *(const bf16x8*)(aBase + 64 * s);
                        bf16x8 a1 = *(const bf16x8*)(aBase + 16 * SH_STRIDE + 64 * s);
                        acc2[0][0] = mfma16(a0, u1[0][js], acc2[0][0]);
                        acc2[1][0] = mfma16(a1, u1[0][js], acc2[1][0]);
                        acc2[0][1] = mfma16(a0, u1[1][js], acc2[0][1]);
                        acc2[1][1] = mfma16(a1, u1[1][js], acc2[1][1]);
                    }
                } else {
                    if (c < 3) LDB(u1, bp0, bp1, c + 1);
#pragma unroll
                    for (int js = 0; js < 2; ++js) {
                        int s = c * 2 + js;
                        bf16x8 a0 = *(const bf16x8*)(aBase + 64 * s);
                        bf16x8 a1 = *(const bf16x8*)(aBase + 16 * SH_STRIDE + 64 * s);
                        acc2[0][0] = mfma16(a0, u0[0][js], acc2[0][0]);
                        acc2[1][0] = mfma16(a1, u0[0][js], acc2[1][0]);
                        acc2[0][1] = mfma16(a0, u0[1][js], acc2[0][1]);
                        acc2[1][1] = mfma16(a1, u0[1][js], acc2[1][1]);
                    }
                }
            }
        }
        // Prefetch next p's L1 chunk 0 -> latency folds into epilogue + barrier.
        if (p < P_ - 1) {
            const unsigned short* bp0 = wt1 + (size_t)(p + 1) * 131072 + bofs;
            LDB(u0, bp0, bp0 + 512, 0);
        }

        // ---- layer 3 from registers: out[p][a] = sum_n tanh(acc2)[a][n]*w3[n] ----
        {
            const float* w3p = W3 + p * H_;
            float prt[8];
#pragma unroll
            for (int k = 0; k < 8; ++k) prt[k] = 0.f;
#pragma unroll
            for (int nt = 0; nt < 2; ++nt) {
                float wv = w3p[w * 32 + nt * 16 + rA];
#pragma unroll
                for (int mt = 0; mt < 2; ++mt)
#pragma unroll
                    for (int i = 0; i < 4; ++i)
                        prt[mt * 4 + i] += fast_tanh(acc2[mt][nt][i]) * wv;
            }
#pragma unroll
            for (int st = 1; st < 16; st <<= 1)
#pragma unroll
                for (int k = 0; k < 8; ++k) prt[k] += __shfl_xor(prt[k], st);
            if (rA == 0) {
                int rg = (lane >> 4) * 4;
#pragma unroll
                for (int mt = 0; mt < 2; ++mt)
#pragma unroll
                    for (int i = 0; i < 4; ++i)
                        atomicAdd(&sOut[p * TA + mt * 16 + rg + i], prt[mt * 4 + i]);
            }
        }
        __syncthreads();   // cH reads done (next p overwrites) + sOut[p] visible
    }

    // ---------------- geometry + energy + segment sum ----------------
    if (tid < TA) {
        int a = aB + tid;
        int i0 = ang[3 * a], i1 = ang[3 * a + 1], i2 = ang[3 * a + 2];
        float ax = xyz[3 * i0], ay = xyz[3 * i0 + 1], az = xyz[3 * i0 + 2];
        float bx = xyz[3 * i1], by = xyz[3 * i1 + 1], bz = xyz[3 * i1 + 2];
        float cx = xyz[3 * i2], cy = xyz[3 * i2 + 1], cz = xyz[3 * i2 + 2];
        float v1x = bx - ax, v1y = by - ay, v1z = bz - az;
        float v2x = cx - bx, v2y = cy - by, v2z = cz - bz;
        float dot = -(v1x * v2x + v1y * v2y + v1z * v2z);
        float n1  = v1x * v1x + v1y * v1y + v1z * v1z;
        float n2  = v2x * v2x + v2y * v2y + v2z * v2z;
        float ct  = dot / sqrtf(n1 * n2);
        float th  = acosf(ct / 1.000001f);

        float o0 = sOut[0 * TA + tid] + b3[0], o1 = sOut[1 * TA + tid] + b3[1];
        float o2 = sOut[2 * TA + tid] + b3[2], o3 = sOut[3 * TA + tid] + b3[3];
        float o4 = sOut[4 * TA + tid] + b3[4], o5 = sOut[5 * TA + tid] + b3[5];
        float t0h = (1.38243827f + o0); t0h *= t0h;       // (sqrt(109.5*pi/180)+o0)^2
        float kh  = (3.16227766f + o1); kh  *= kh;        // (sqrt(10)+o1)^2
        float d   = th - t0h;
        float E   = 0.5f * kh * d * d;
        float t0c = o2 * o2, kc = o3 * o3;
        float dc  = th - t0c;
        E += 0.5f * kc * dc * dc * dc;
        float t0q = o4 * o4, kq = o5 * o5;
        float dq  = th - t0q;
        E += 0.5f * kq * dq * dq * dq * dq;

        int lo = 0, hi = BSEG - 1;                        // last s with prefix[s] <= a
        while (lo < hi) { int mid = (lo + hi + 1) >> 1; if (prefix[mid] <= a) lo = mid; else hi = mid - 1; }
        atomicAdd(&sSeg[lo], E);
    }
    __syncthreads();
    if (tid < BSEG) {
        float v = sSeg[tid];
        if (v != 0.f) atomicAdd(out + tid, v);
    }
}

extern "C" void kernel_launch(void* const* d_in, const int* in_sizes, int n_in,
                              void* d_out, int out_size, void* d_ws, size_t ws_size,
                              hipStream_t stream) {
    const float* r   = (const float*)d_in[0];
    const float* xyz = (const float*)d_in[1];
    const int*   ang = (const int*)d_in[2];
    const int*   na  = (const int*)d_in[3];
    const float* W1  = (const float*)d_in[4];
    const float* b1  = (const float*)d_in[5];
    const float* W2  = (const float*)d_in[6];
    const float* b2  = (const float*)d_in[7];
    const float* W3  = (const float*)d_in[8];
    const float* b3  = (const float*)d_in[9];
    float* out = (float*)d_out;

    char* ws = (char*)d_ws;
    int* prefix          = (int*)ws;                              // 101 ints (512B reserved)
    unsigned short* wt1  = (unsigned short*)(ws + 512);           // 1.5 MB bf16 frag-linear
    unsigned short* wt2  = (unsigned short*)(ws + 512 + 1572864); // 0.75 MB

    prep_kernel<<<576, 256, 0, stream>>>(W1, W2, na, out, prefix, wt1, wt2);
    int nblk = A_TOTAL / TA;   // 6250, exact
    angle_main<<<nblk, NTHREADS, 0, stream>>>(r, xyz, ang, b1, b2, W3, b3, out, prefix, wt1, wt2);
}

// Round 10
// 608.740 us; speedup vs baseline: 1.0776x; 1.0776x over previous
//
#include <hip/hip_runtime.h>
#include <hip/hip_bf16.h>

#define A_TOTAL  200000
#define BSEG     100
#define FR_      256
#define DIN_     512
#define H_       256
#define P_       6
#define TA       32
#define NTHREADS 256

#define SNI_STRIDE 1040   // 512 bf16 = 1024B + 16B pad
#define SH_STRIDE  528    // 256 bf16 = 512B + 16B pad

typedef float f32x4  __attribute__((ext_vector_type(4)));
typedef short bf16x8 __attribute__((ext_vector_type(8)));

__device__ __forceinline__ unsigned short f2bf(float x) {
    union { float f; unsigned int u; } c; c.f = x;
    unsigned int u = c.u;
    return (unsigned short)((u + 0x7fffu + ((u >> 16) & 1u)) >> 16);
}
__device__ __forceinline__ unsigned int pk2(float a, float b) {   // v_cvt_pk_bf16_f32
    union { __hip_bfloat162 h2; unsigned int u; } c;
    c.h2 = __float22bfloat162_rn(float2{a, b});
    return c.u;
}
__device__ __forceinline__ float fast_tanh(float x) {
    float e = __builtin_amdgcn_exp2f(x * 2.88539008177793f);  // e^{2x}
    float r = __builtin_amdgcn_rcpf(e + 1.f);
    return __builtin_fmaf(-2.f, r, 1.f);
}
__device__ __forceinline__ f32x4 mfma16(bf16x8 a, bf16x8 b, f32x4 c) {
    return __builtin_amdgcn_mfma_f32_16x16x32_bf16(a, b, c, 0, 0, 0);
}

// VALU-pipe 16-lane sum via DPP row rotate (replaces ds_bpermute shuffles).
#define DPP_ROR_ADD(v, CTRL)                                                      \
    do { union { float f; int i; } _s, _d; _s.f = (v);                            \
         _d.i = __builtin_amdgcn_update_dpp(0, _s.i, (CTRL), 0xf, 0xf, false);    \
         (v) += _d.f; } while (0)
#define DPP_SUM16(v) { DPP_ROR_ADD(v, 0x121); DPP_ROR_ADD(v, 0x122); \
                       DPP_ROR_ADD(v, 0x124); DPP_ROR_ADD(v, 0x128); }

// ---------------------------------------------------------------------------
// Prep: W1/W2 -> bf16 fragment-linear layout; prefix-sum num_angles; zero out.
// B-frag for 16x16x32: lane l holds B[k = s*32 + 8*(l>>4) + j][n = nt*16 + (l&15)]
// stored as wt[p][s][ntile][lane][j].
// ---------------------------------------------------------------------------
__global__ void prep_kernel(const float* __restrict__ W1, const float* __restrict__ W2,
                            const int* __restrict__ num_angles, float* __restrict__ out,
                            int* __restrict__ prefix,
                            unsigned short* __restrict__ wt1, unsigned short* __restrict__ wt2) {
    int tt = blockIdx.x * blockDim.x + threadIdx.x;
    if (blockIdx.x == 0) {
        if (threadIdx.x < BSEG) out[threadIdx.x] = 0.f;
        if (threadIdx.x == 0) {
            int acc = 0; prefix[0] = 0;
            for (int i = 0; i < BSEG; ++i) { acc += num_angles[i]; prefix[i + 1] = acc; }
        }
    }
    if (tt < 98304) {                       // W1: 6 p * 16 s * 16 nt * 64 lanes
        int l  = tt & 63;
        int nt = (tt >> 6) & 15;
        int s  = (tt >> 10) & 15;
        int p  = tt >> 14;
        int k  = s * 32 + 8 * (l >> 4);
        int n  = nt * 16 + (l & 15);
        const float* src = W1 + ((size_t)p * DIN_ + k) * H_ + n;
        unsigned short tmp[8];
#pragma unroll
        for (int j = 0; j < 8; ++j) tmp[j] = f2bf(src[(size_t)j * H_]);
        *reinterpret_cast<uint4*>(wt1 + (size_t)tt * 8) = *reinterpret_cast<uint4*>(tmp);
    } else if (tt < 98304 + 49152) {        // W2: 6 p * 8 s * 16 nt * 64 lanes
        int t2 = tt - 98304;
        int l  = t2 & 63;
        int nt = (t2 >> 6) & 15;
        int s  = (t2 >> 10) & 7;
        int p  = t2 >> 13;
        int k  = s * 32 + 8 * (l >> 4);
        int n  = nt * 16 + (l & 15);
        const float* src = W2 + ((size_t)p * H_ + k) * H_ + n;
        unsigned short tmp[8];
#pragma unroll
        for (int j = 0; j < 8; ++j) tmp[j] = f2bf(src[(size_t)j * H_]);
        *reinterpret_cast<uint4*>(wt2 + (size_t)t2 * 8) = *reinterpret_cast<uint4*>(tmp);
    }
}

// Load the 4 ntiles of one s-step into a 4-frag buffer.
#define LD4(dst, bp, s)                                                          \
    { dst[0] = *(const bf16x8*)((bp) + (size_t)(s) * 8192);                      \
      dst[1] = *(const bf16x8*)((bp) + (size_t)(s) * 8192 + 512);                \
      dst[2] = *(const bf16x8*)((bp) + (size_t)(s) * 8192 + 1024);               \
      dst[3] = *(const bf16x8*)((bp) + (size_t)(s) * 8192 + 1536); }

// One s-step: prefetch s+2 into UP (freed buffer), ds_read 2 A-frags, 8 MFMA.
#define GSTEP(s, SMAX, UC, UP, bp, aBase, STRIDE, ac)                            \
    { if ((s) + 2 < (SMAX)) LD4(UP, bp, (s) + 2);                                \
      bf16x8 a0 = *(const bf16x8*)((aBase) + 64 * (s));                          \
      bf16x8 a1 = *(const bf16x8*)((aBase) + 16 * (STRIDE) + 64 * (s));          \
      ac[0][0] = mfma16(a0, UC[0], ac[0][0]);                                    \
      ac[1][0] = mfma16(a1, UC[0], ac[1][0]);                                    \
      ac[0][1] = mfma16(a0, UC[1], ac[0][1]);                                    \
      ac[1][1] = mfma16(a1, UC[1], ac[1][1]);                                    \
      ac[0][2] = mfma16(a0, UC[2], ac[0][2]);                                    \
      ac[1][2] = mfma16(a1, UC[2], ac[1][2]);                                    \
      ac[0][3] = mfma16(a0, UC[3], ac[0][3]);                                    \
      ac[1][3] = mfma16(a1, UC[3], ac[1][3]); }

// ---------------------------------------------------------------------------
// Main fused kernel: TA=32 angles/block, 4 waves of fat tiles (32 rows x 64
// cols each). Halves LDS A-read traffic per MFMA vs nt=2. 3-buffer rotating
// B-prefetch (2 s-steps ahead); cross-barrier weight hoists; DPP layer-3
// reduction (VALU pipe, no LDS). LDS 51.3 KB -> 3 blocks/CU.
// ---------------------------------------------------------------------------
__global__ __launch_bounds__(NTHREADS, 4)
void angle_main(const float* __restrict__ r, const float* __restrict__ xyz,
                const int* __restrict__ ang,
                const float* __restrict__ b1, const float* __restrict__ b2,
                const float* __restrict__ W3, const float* __restrict__ b3,
                float* __restrict__ out, const int* __restrict__ prefix,
                const unsigned short* __restrict__ wt1, const unsigned short* __restrict__ wt2) {
    __shared__ __align__(16) char cNI[TA * SNI_STRIDE];  // 33280 B
    __shared__ __align__(16) char cH[TA * SH_STRIDE];    // 16896 B
    __shared__ float sOut[P_ * TA];
    __shared__ float sSeg[BSEG];

    const int tid  = threadIdx.x;
    const int lane = tid & 63;
    const int w    = tid >> 6;        // wave id 0..3: owns cols [w*64, w*64+64)
    const int aB   = blockIdx.x * TA;
    const int rA   = lane & 15;       // A-frag row within 16-tile
    const int q16  = 16 * (lane >> 4);// A-frag k-subgroup byte offset

    if (tid < P_ * TA) sOut[tid] = 0.f;
    if (tid < BSEG)    sSeg[tid] = 0.f;

    // Per-wave weight fragment base offset: ntile group w*4.
    const size_t bofs = (size_t)(w * 4) * 512 + (size_t)lane * 8;
    bf16x8 u0[4], u1[4], u2[4];       // rotating B buffers (live across barriers)

    // Hoist p=0 L1 s=0 above the gather barrier.
    LD4(u0, wt1 + bofs, 0);

    // ---- gather node_input = [r[a0]+r[a2], r[a1]] -> LDS bf16 ----
#pragma unroll
    for (int it = 0; it < 8; ++it) {
        int c   = it * NTHREADS + tid;       // 2048 chunks of 8 elems
        int row = c >> 6;
        int k0  = (c & 63) * 8;
        int a   = aB + row;
        int i0 = ang[3 * a], i1 = ang[3 * a + 1], i2 = ang[3 * a + 2];
        float v[8];
        if (k0 < FR_) {
            const float4* p0 = (const float4*)(r + (size_t)i0 * FR_ + k0);
            const float4* p2 = (const float4*)(r + (size_t)i2 * FR_ + k0);
            float4 x0 = p0[0], x1 = p0[1], y0 = p2[0], y1 = p2[1];
            v[0] = x0.x + y0.x; v[1] = x0.y + y0.y; v[2] = x0.z + y0.z; v[3] = x0.w + y0.w;
            v[4] = x1.x + y1.x; v[5] = x1.y + y1.y; v[6] = x1.z + y1.z; v[7] = x1.w + y1.w;
        } else {
            const float4* p1 = (const float4*)(r + (size_t)i1 * FR_ + (k0 - FR_));
            float4 x0 = p1[0], x1 = p1[1];
            v[0] = x0.x; v[1] = x0.y; v[2] = x0.z; v[3] = x0.w;
            v[4] = x1.x; v[5] = x1.y; v[6] = x1.z; v[7] = x1.w;
        }
        uint4 pk;
        pk.x = pk2(v[0], v[1]); pk.y = pk2(v[2], v[3]);
        pk.z = pk2(v[4], v[5]); pk.w = pk2(v[6], v[7]);
        *reinterpret_cast<uint4*>(cNI + row * SNI_STRIDE + k0 * 2) = pk;
    }
    __syncthreads();
    LD4(u1, wt1 + bofs, 1);   // p=0 L1 s=1

    for (int p = 0; p < P_; ++p) {
        const unsigned short* bp1 = wt1 + (size_t)p * 131072 + bofs;
        const unsigned short* bp2 = wt2 + (size_t)p * 65536 + bofs;
        const int colbase = w * 64 + rA;

        // ---------------- layer 1: [32x512] @ [512x256], 64 cols/wave ----
        f32x4 acc[2][4];
#pragma unroll
        for (int nt = 0; nt < 4; ++nt) {
            float b = b1[p * H_ + colbase + nt * 16];
            acc[0][nt] = (f32x4){b, b, b, b};
            acc[1][nt] = acc[0][nt];
        }
        {
            const char* aBase = cNI + rA * SNI_STRIDE + q16;
            // u0=s0, u1=s1 already loaded (cross-barrier hoist)
            GSTEP( 0, 16, u0, u2, bp1, aBase, SNI_STRIDE, acc);
            GSTEP( 1, 16, u1, u0, bp1, aBase, SNI_STRIDE, acc);
            GSTEP( 2, 16, u2, u1, bp1, aBase, SNI_STRIDE, acc);
            GSTEP( 3, 16, u0, u2, bp1, aBase, SNI_STRIDE, acc);
            GSTEP( 4, 16, u1, u0, bp1, aBase, SNI_STRIDE, acc);
            GSTEP( 5, 16, u2, u1, bp1, aBase, SNI_STRIDE, acc);
            GSTEP( 6, 16, u0, u2, bp1, aBase, SNI_STRIDE, acc);
            GSTEP( 7, 16, u1, u0, bp1, aBase, SNI_STRIDE, acc);
            GSTEP( 8, 16, u2, u1, bp1, aBase, SNI_STRIDE, acc);
            GSTEP( 9, 16, u0, u2, bp1, aBase, SNI_STRIDE, acc);
            GSTEP(10, 16, u1, u0, bp1, aBase, SNI_STRIDE, acc);
            GSTEP(11, 16, u2, u1, bp1, aBase, SNI_STRIDE, acc);
            GSTEP(12, 16, u0, u2, bp1, aBase, SNI_STRIDE, acc);
            GSTEP(13, 16, u1, u0, bp1, aBase, SNI_STRIDE, acc);
            GSTEP(14, 16, u2, u1, bp1, aBase, SNI_STRIDE, acc);
            GSTEP(15, 16, u0, u2, bp1, aBase, SNI_STRIDE, acc);
        }
        // Hoist L2 s0/s1 loads above the tanh epilogue + barrier.
        LD4(u0, bp2, 0);
        LD4(u1, bp2, 1);
        {   // tanh + packed bf16 -> cH (D layout: row = 4*(l>>4)+i, col = l&15)
#pragma unroll
            for (int nt = 0; nt < 4; ++nt) {
                int col = colbase + nt * 16;
#pragma unroll
                for (int mt = 0; mt < 2; ++mt) {
                    float t0 = fast_tanh(acc[mt][nt][0]);
                    float t1 = fast_tanh(acc[mt][nt][1]);
                    float t2 = fast_tanh(acc[mt][nt][2]);
                    float t3 = fast_tanh(acc[mt][nt][3]);
                    unsigned int u01 = pk2(t0, t1);
                    unsigned int u23 = pk2(t2, t3);
                    char* base = cH + (mt * 16 + (lane >> 4) * 4) * SH_STRIDE + col * 2;
                    *(unsigned short*)(base)                 = (unsigned short)(u01 & 0xffff);
                    *(unsigned short*)(base + SH_STRIDE)     = (unsigned short)(u01 >> 16);
                    *(unsigned short*)(base + 2 * SH_STRIDE) = (unsigned short)(u23 & 0xffff);
                    *(unsigned short*)(base + 3 * SH_STRIDE) = (unsigned short)(u23 >> 16);
                }
            }
        }
        __syncthreads();

        // ---------------- layer 2: [32x256] @ [256x256] ----------------
        f32x4 acc2[2][4];
#pragma unroll
        for (int nt = 0; nt < 4; ++nt) {
            float b = b2[p * H_ + colbase + nt * 16];
            acc2[0][nt] = (f32x4){b, b, b, b};
            acc2[1][nt] = acc2[0][nt];
        }
        {
            const char* aBase = cH + rA * SH_STRIDE + q16;
            // u0=s0, u1=s1 hoisted above the barrier
            GSTEP(0, 8, u0, u2, bp2, aBase, SH_STRIDE, acc2);
            GSTEP(1, 8, u1, u0, bp2, aBase, SH_STRIDE, acc2);
            GSTEP(2, 8, u2, u1, bp2, aBase, SH_STRIDE, acc2);
            GSTEP(3, 8, u0, u2, bp2, aBase, SH_STRIDE, acc2);
            GSTEP(4, 8, u1, u0, bp2, aBase, SH_STRIDE, acc2);
            GSTEP(5, 8, u2, u1, bp2, aBase, SH_STRIDE, acc2);
            GSTEP(6, 8, u0, u2, bp2, aBase, SH_STRIDE, acc2);
            GSTEP(7, 8, u1, u0, bp2, aBase, SH_STRIDE, acc2);
        }
        // Hoist next-p L1 s0/s1 above the layer-3 epilogue + barrier.
        if (p < P_ - 1) {
            const unsigned short* bpn = wt1 + (size_t)(p + 1) * 131072 + bofs;
            LD4(u0, bpn, 0);
            LD4(u1, bpn, 1);
        }

        // ---- layer 3: out[p][a] = sum_n tanh(acc2)[a][n]*w3[n], DPP reduce ----
        {
            const float* w3p = W3 + p * H_;
            float prt[8];
#pragma unroll
            for (int k = 0; k < 8; ++k) prt[k] = 0.f;
#pragma unroll
            for (int nt = 0; nt < 4; ++nt) {
                float wv = w3p[colbase + nt * 16];
#pragma unroll
                for (int mt = 0; mt < 2; ++mt)
#pragma unroll
                    for (int i = 0; i < 4; ++i)
                        prt[mt * 4 + i] += fast_tanh(acc2[mt][nt][i]) * wv;
            }
#pragma unroll
            for (int k = 0; k < 8; ++k) DPP_SUM16(prt[k]);
            if (rA == 0) {
                int rg = (lane >> 4) * 4;
#pragma unroll
                for (int mt = 0; mt < 2; ++mt)
#pragma unroll
                    for (int i = 0; i < 4; ++i)
                        atomicAdd(&sOut[p * TA + mt * 16 + rg + i], prt[mt * 4 + i]);
            }
        }
        __syncthreads();   // cH reads done (next p overwrites) + sOut[p] visible
    }

    // ---------------- geometry + energy + segment sum ----------------
    if (tid < TA) {
        int a = aB + tid;
        int i0 = ang[3 * a], i1 = ang[3 * a + 1], i2 = ang[3 * a + 2];
        float ax = xyz[3 * i0], ay = xyz[3 * i0 + 1], az = xyz[3 * i0 + 2];
        float bx = xyz[3 * i1], by = xyz[3 * i1 + 1], bz = xyz[3 * i1 + 2];
        float cx = xyz[3 * i2], cy = xyz[3 * i2 + 1], cz = xyz[3 * i2 + 2];
        float v1x = bx - ax, v1y = by - ay, v1z = bz - az;
        float v2x = cx - bx, v2y = cy - by, v2z = cz - bz;
        float dot = -(v1x * v2x + v1y * v2y + v1z * v2z);
        float n1  = v1x * v1x + v1y * v1y + v1z * v1z;
        float n2  = v2x * v2x + v2y * v2y + v2z * v2z;
        float ct  = dot / sqrtf(n1 * n2);
        float th  = acosf(ct / 1.000001f);

        float o0 = sOut[0 * TA + tid] + b3[0], o1 = sOut[1 * TA + tid] + b3[1];
        float o2 = sOut[2 * TA + tid] + b3[2], o3 = sOut[3 * TA + tid] + b3[3];
        float o4 = sOut[4 * TA + tid] + b3[4], o5 = sOut[5 * TA + tid] + b3[5];
        float t0h = (1.38243827f + o0); t0h *= t0h;       // (sqrt(109.5*pi/180)+o0)^2
        float kh  = (3.16227766f + o1); kh  *= kh;        // (sqrt(10)+o1)^2
        float d   = th - t0h;
        float E   = 0.5f * kh * d * d;
        float t0c = o2 * o2, kc = o3 * o3;
        float dc  = th - t0c;
        E += 0.5f * kc * dc * dc * dc;
        float t0q = o4 * o4, kq = o5 * o5;
        float dq  = th - t0q;
        E += 0.5f * kq * dq * dq * dq * dq;

        int lo = 0, hi = BSEG - 1;                        // last s with prefix[s] <= a
        while (lo < hi) { int mid = (lo + hi + 1) >> 1; if (prefix[mid] <= a) lo = mid; else hi = mid - 1; }
        atomicAdd(&sSeg[lo], E);
    }
    __syncthreads();
    if (tid < BSEG) {
        float v = sSeg[tid];
        if (v != 0.f) atomicAdd(out + tid, v);
    }
}

extern "C" void kernel_launch(void* const* d_in, const int* in_sizes, int n_in,
                              void* d_out, int out_size, void* d_ws, size_t ws_size,
                              hipStream_t stream) {
    const float* r   = (const float*)d_in[0];
    const float* xyz = (const float*)d_in[1];
    const int*   ang = (const int*)d_in[2];
    const int*   na  = (const int*)d_in[3];
    const float* W1  = (const float*)d_in[4];
    const float* b1  = (const float*)d_in[5];
    const float* W2  = (const float*)d_in[6];
    const float* b2  = (const float*)d_in[7];
    const float* W3  = (const float*)d_in[8];
    const float* b3  = (const float*)d_in[9];
    float* out = (float*)d_out;

    char* ws = (char*)d_ws;
    int* prefix          = (int*)ws;                              // 101 ints (512B reserved)
    unsigned short* wt1  = (unsigned short*)(ws + 512);           // 1.5 MB bf16 frag-linear
    unsigned short* wt2  = (unsigned short*)(ws + 512 + 1572864); // 0.75 MB

    prep_kernel<<<576, 256, 0, stream>>>(W1, W2, na, out, prefix, wt1, wt2);
    int nblk = A_TOTAL / TA;   // 6250, exact
    angle_main<<<nblk, NTHREADS, 0, stream>>>(r, xyz, ang, b1, b2, W3, b3, out, prefix, wt1, wt2);
}